// Round 1
// 608.814 us; speedup vs baseline: 1.0322x; 1.0322x over previous
//
#include <hip/hip_runtime.h>
#include <cstdint>
#include <cstddef>

// Problem constants: B=32, LQ=LA=1024, H=512
#define NB   32
#define LQA  1024   // LQ == LA
#define HD   512

typedef __attribute__((ext_vector_type(4))) float  f32x4;
typedef __attribute__((ext_vector_type(8))) short  s16x8;   // 8 bf16 (4 VGPRs) MFMA frag
typedef __attribute__((ext_vector_type(4))) unsigned short u16x4;

static __device__ __forceinline__ unsigned short f2bf(float f) {
  unsigned int u = __builtin_bit_cast(unsigned int, f);
  u += 0x7fffu + ((u >> 16) & 1u);      // RNE
  return (unsigned short)(u >> 16);
}
static __device__ __forceinline__ float bf2f(unsigned short h) {
  unsigned int u = ((unsigned int)h) << 16;
  return __builtin_bit_cast(float, u);
}
static __device__ __forceinline__ u16x4 cvt4(f32x4 v) {
  u16x4 r;
  r.x = f2bf(v.x); r.y = f2bf(v.y); r.z = f2bf(v.z); r.w = f2bf(v.w);
  return r;
}

// async global->LDS, 16B per lane; lds base must be wave-uniform (HW scatters
// lane i at base + i*16)
typedef __attribute__((address_space(1))) const void gas_void;
typedef __attribute__((address_space(3))) void las_void;
static __device__ __forceinline__ void gload_lds16(const void* g, void* l) {
  __builtin_amdgcn_global_load_lds((gas_void*)g, (las_void*)l, 16, 0, 0);
}

// ---------------------------------------------------------------------------
// K0: per-batch 64x64 tiled: fp32 [LQA x HD] ->
//   (a) fp32 copy into concat-output left half,
//   (b) bf16 transposed copy [HD x LQA]  (for aggregation-GEMM B operands),
//   (c) bf16 row-major copy [LQA x HD]   (for score-GEMM operands).
// grid: (HD/64=8, LQA/64=16, NB), block 256
// ---------------------------------------------------------------------------
__global__ __launch_bounds__(256) void k_transpose_copy(
    const float* __restrict__ src,        // [NB][LQA][HD]
    float* __restrict__ out_left,         // [NB][LQA][1024], cols 0..511
    unsigned short* __restrict__ dstT,    // [NB][HD][LQA] bf16
    unsigned short* __restrict__ dstN)    // [NB][LQA][HD] bf16
{
  const int b  = blockIdx.z;
  const int h0 = blockIdx.x * 64;
  const int q0 = blockIdx.y * 64;
  const int t  = threadIdx.x;

  __shared__ unsigned short T[64 * 68];

  const float* sb = src + (size_t)b * LQA * HD;
  float* ob       = out_left + (size_t)b * LQA * 1024;
  unsigned short* db  = dstT + (size_t)b * HD * LQA;
  unsigned short* dbn = dstN + (size_t)b * LQA * HD;

#pragma unroll
  for (int j = 0; j < 4; ++j) {
    int f = t + 256 * j;
    int r = f >> 4;            // 0..63 (q-local)
    int c = (f & 15) * 4;      // 0..60 (h-local)
    f32x4 v = *(const f32x4*)(sb + (size_t)(q0 + r) * HD + h0 + c);
    *(f32x4*)(ob + (size_t)(q0 + r) * 1024 + h0 + c) = v;   // concat left half
    u16x4 cv = cvt4(v);
    *(u16x4*)&dbn[(size_t)(q0 + r) * HD + h0 + c] = cv;     // row-major bf16
    *(u16x4*)&T[r * 68 + c] = cv;
  }
  __syncthreads();
#pragma unroll
  for (int j = 0; j < 4; ++j) {
    int f = t + 256 * j;
    int orow = f >> 4;         // 0..63 (h-local)
    int c = (f & 15) * 4;      // 0..60 (q-local)
    u16x4 v;
    v.x = T[(c + 0) * 68 + orow];
    v.y = T[(c + 1) * 68 + orow];
    v.z = T[(c + 2) * 68 + orow];
    v.w = T[(c + 3) * 68 + orow];
    *(u16x4*)&db[(size_t)(h0 + orow) * LQA + q0 + c] = v;
  }
}

// ---------------------------------------------------------------------------
// K1: scores. E[b,q,a] = qm*am*exp(temp * dot(q,a)); writes E and E^T (bf16),
// plus fused atomic partial row sums (over a) and col sums (over q) of E —
// replaces the two k_rowsum_stats passes (saves 128 MB of E/ET re-reads).
// 128x128 tile, BK=32, global_load_lds(16B) staging from bf16 copies.
// grid: flat 2048 = 8 mt x 8 nt x NB, XCD-batch-locality swizzled; block 256.
// ---------------------------------------------------------------------------
__global__ __launch_bounds__(256) void k_scores(
    const unsigned short* __restrict__ qb16, const unsigned short* __restrict__ ab16,
    const int* __restrict__ qmask, const int* __restrict__ amask,
    const float* __restrict__ temp_p,
    unsigned short* __restrict__ E, unsigned short* __restrict__ ET,
    float* __restrict__ rowsumE,    // [NB*LQA], pre-zeroed; sum over a per (b,q)
    float* __restrict__ colsumE)    // [NB*LQA], pre-zeroed; sum over q per (b,a)
{
  // XCD-aware decode: each XCD (flat&7) owns whole batches -> per-XCD L2
  // working set = qb16+ab16 slices of its own batches only.
  const int flat = blockIdx.x;          // 0..2047
  const int xcd  = flat & 7;
  const int i5   = flat >> 3;           // 0..255
  const int b    = (i5 >> 6) * 8 + xcd; // 0..31
  const int tile = i5 & 63;
  const int m0 = (tile & 7) * 128;
  const int n0 = (tile >> 3) * 128;

  const int t  = threadIdx.x;
  const int lane = t & 63;
  const int w  = t >> 6;
  const int moff = (w & 1) * 64;
  const int noff = (w >> 1) * 64;
  const int lrow = lane & 15;
  const int quad = lane >> 4;

  // As/Bs (8KB each) alias the epilogue Cs buffer (128*132 ushort = 33.8KB)
  __shared__ __align__(16) unsigned short smem[128 * 132];
  unsigned short* As = smem;          // [128][32]
  unsigned short* Bs = smem + 4096;   // [128][32]

  const unsigned short* qb = qb16 + (size_t)b * LQA * HD;
  const unsigned short* ab = ab16 + (size_t)b * LQA * HD;

  // staging: chunk f covers row f>>2, k-chunk (f&3)*8; pass p: f = t + 256*p
  const int fa = t, fb = t + 256;
  const unsigned short* qg0 = qb + (size_t)(m0 + (fa >> 2)) * HD + (fa & 3) * 8;
  const unsigned short* qg1 = qb + (size_t)(m0 + (fb >> 2)) * HD + (fb & 3) * 8;
  const unsigned short* ag0 = ab + (size_t)(n0 + (fa >> 2)) * HD + (fa & 3) * 8;
  const unsigned short* ag1 = ab + (size_t)(n0 + (fb >> 2)) * HD + (fb & 3) * 8;
  unsigned short* As0 = As + w * 512;          // wave-uniform LDS bases
  unsigned short* As1 = As + (4 + w) * 512;
  unsigned short* Bs0 = Bs + w * 512;
  unsigned short* Bs1 = Bs + (4 + w) * 512;

  f32x4 acc[4][4];
#pragma unroll
  for (int i = 0; i < 4; ++i)
#pragma unroll
    for (int j = 0; j < 4; ++j) acc[i][j] = (f32x4)0.f;

  for (int kt = 0; kt < HD / 32; ++kt) {
    const int ko = kt * 32;
    gload_lds16(qg0 + ko, As0);
    gload_lds16(qg1 + ko, As1);
    gload_lds16(ag0 + ko, Bs0);
    gload_lds16(ag1 + ko, Bs1);
    __syncthreads();
    s16x8 af[4], bfr[4];
#pragma unroll
    for (int i = 0; i < 4; ++i) {
      af[i]  = *(const s16x8*)&As[(moff + i * 16 + lrow) * 32 + quad * 8];
      bfr[i] = *(const s16x8*)&Bs[(noff + i * 16 + lrow) * 32 + quad * 8];
    }
#pragma unroll
    for (int i = 0; i < 4; ++i)
#pragma unroll
      for (int j = 0; j < 4; ++j)
        acc[i][j] = __builtin_amdgcn_mfma_f32_16x16x32_bf16(af[i], bfr[j], acc[i][j], 0, 0, 0);
    __syncthreads();
  }

  // Epilogue: temp/mask/exp -> Cs (bf16), partial sums, then E / E^T writes.
  unsigned short* Cs = smem;   // [128][132], safe after final barrier
  const float temp = temp_p[0];
  const int* qmb = qmask + b * LQA;
  const int* amb = amask + b * LQA;

  float rowp[4][4];            // [i][r] partial row sums (this thread's 4 cols)
  float colp[4];               // [j]    partial col sums (this thread's 16 rows)
#pragma unroll
  for (int i = 0; i < 4; ++i)
#pragma unroll
    for (int r = 0; r < 4; ++r) rowp[i][r] = 0.f;
#pragma unroll
  for (int j = 0; j < 4; ++j) colp[j] = 0.f;

#pragma unroll
  for (int i = 0; i < 4; ++i) {
#pragma unroll
    for (int j = 0; j < 4; ++j) {
      int ncol = noff + j * 16 + lrow;
      float am = (amb[n0 + ncol] != 0) ? 1.f : 0.f;
#pragma unroll
      for (int r = 0; r < 4; ++r) {
        int mrow = moff + i * 16 + quad * 4 + r;
        float qm = (qmb[m0 + mrow] != 0) ? 1.f : 0.f;
        float e = __expf(acc[i][j][r] * temp) * am * qm;
        unsigned short eb = f2bf(e);
        float er = bf2f(eb);               // sum the ROUNDED value: matches the
        Cs[mrow * 132 + ncol] = eb;        // numerics of the old E re-read pass
        rowp[i][r] += er;
        colp[j] += er;
      }
    }
  }

  // row sums: lanes lrow=0..15 of each quad hold disjoint 4-col partials of
  // the same row -> 16-lane butterfly, one atomic per row per wave.
#pragma unroll
  for (int i = 0; i < 4; ++i)
#pragma unroll
    for (int r = 0; r < 4; ++r) {
      float v = rowp[i][r];
      v += __shfl_xor(v, 1); v += __shfl_xor(v, 2);
      v += __shfl_xor(v, 4); v += __shfl_xor(v, 8);
      if (lrow == 0)
        atomicAdd(&rowsumE[(size_t)b * LQA + m0 + moff + i * 16 + quad * 4 + r], v);
    }
  // col sums: quads 0..3 hold disjoint 16-row partials of the same col.
#pragma unroll
  for (int j = 0; j < 4; ++j) {
    float v = colp[j];
    v += __shfl_xor(v, 16); v += __shfl_xor(v, 32);
    if (quad == 0)
      atomicAdd(&colsumE[(size_t)b * LQA + n0 + noff + j * 16 + lrow], v);
  }

  __syncthreads();
  const size_t Ebase = (size_t)b * LQA * LQA;
#pragma unroll
  for (int jj = 0; jj < 16; ++jj) {
    int f = t + 256 * jj;
    int row = f >> 5;            // 0..127
    int c = (f & 31) * 4;        // 0..124
    u16x4 v = *(const u16x4*)&Cs[row * 132 + c];
    *(u16x4*)&E[Ebase + (size_t)(m0 + row) * LQA + n0 + c] = v;
  }
#pragma unroll
  for (int jj = 0; jj < 16; ++jj) {
    int f = t + 256 * jj;
    int orow = f >> 5;           // a-local
    int c = (f & 31) * 4;        // q-local
    u16x4 v;
    v.x = Cs[(c + 0) * 132 + orow];
    v.y = Cs[(c + 1) * 132 + orow];
    v.z = Cs[(c + 2) * 132 + orow];
    v.w = Cs[(c + 3) * 132 + orow];
    *(u16x4*)&ET[Ebase + (size_t)(n0 + orow) * LQA + m0 + c] = v;
  }
}

// ---------------------------------------------------------------------------
// K2b: plain row sums of bf16 [NROWS x LQA] -> float. Used on qT/aT to get
// per-(b,h) column sums of q/a (for the all-masked uniform-softmax term).
// ---------------------------------------------------------------------------
__global__ __launch_bounds__(256) void k_rowsum_plain(
    const unsigned short* __restrict__ M, float* __restrict__ sums)
{
  const int t = threadIdx.x;
  const int rowg = blockIdx.x * 16 + (t >> 4);
  const int s = t & 15;
  const unsigned short* rp = M + (size_t)rowg * LQA;
  float sum = 0.f;
#pragma unroll
  for (int it = 0; it < 16; ++it) {
    u16x4 v = *(const u16x4*)&rp[it * 64 + s * 4];
    sum += bf2f(v.x) + bf2f(v.y) + bf2f(v.z) + bf2f(v.w);
  }
  sum += __shfl_xor(sum, 1);
  sum += __shfl_xor(sum, 2);
  sum += __shfl_xor(sum, 4);
  sum += __shfl_xor(sum, 8);
  if (s == 0) sums[rowg] = sum;
}

// ---------------------------------------------------------------------------
// K2c: sums -> (inv, add) per row.  inv = 1/sum, add = 0 if sum>0,
// else inv=0, add=1/1024.  Covers rowsumE and colsumE in one launch.
// ---------------------------------------------------------------------------
__global__ __launch_bounds__(256) void k_stats(
    const float* __restrict__ sums, float2* __restrict__ invadd)
{
  const int idx = blockIdx.x * 256 + threadIdx.x;
  float s = sums[idx];
  float2 o;
  if (s > 0.f) { o.x = 1.f / s; o.y = 0.f; }
  else         { o.x = 0.f;     o.y = 1.f / 1024.f; }
  invadd[idx] = o;
}

// ---------------------------------------------------------------------------
// K3: aggregation GEMM (pure bf16, normalization factored into epilogue):
//   out[b,m,512+n] = inv[m] * sum_k Emat[m,k]*Bt[n,k]  +  add[m] * bsum[n]
// Emat: [NB][LQA][LQA] (E or E^T), Bt: [NB][HD][LQA], bsum: [NB][HD].
// grid: flat 1024 = 8 mt x 4 nt x NB, XCD-batch-locality swizzled; block 256.
// ---------------------------------------------------------------------------
__global__ __launch_bounds__(256) void k_agg(
    const unsigned short* __restrict__ Emat,
    const unsigned short* __restrict__ Bt,
    const float2* __restrict__ invadd,
    const float* __restrict__ bsum,
    float* __restrict__ outp)
{
  // XCD-aware decode: XCD (flat&7) owns whole batches -> per-XCD working set
  // = 4 batches x (E slice 2MB + Bt slice 1MB), mostly L2-resident.
  const int flat = blockIdx.x;          // 0..1023
  const int xcd  = flat & 7;
  const int i5   = flat >> 3;           // 0..127
  const int b    = (i5 >> 5) * 8 + xcd; // 0..31
  const int tile = i5 & 31;
  const int m0 = (tile & 7) * 128;
  const int n0 = (tile >> 3) * 128;     // h tile (< 512)

  const int t  = threadIdx.x;
  const int lane = t & 63;
  const int w  = t >> 6;
  const int moff = (w & 1) * 64;
  const int noff = (w >> 1) * 64;
  const int lrow = lane & 15;
  const int quad = lane >> 4;

  __shared__ __align__(16) unsigned short As[128 * 32];
  __shared__ __align__(16) unsigned short Bs[128 * 32];

  const unsigned short* Eb = Emat + (size_t)b * LQA * LQA;
  const unsigned short* Bb = Bt + (size_t)b * HD * LQA;

  const int fa = t, fb = t + 256;
  const unsigned short* eg0 = Eb + (size_t)(m0 + (fa >> 2)) * LQA + (fa & 3) * 8;
  const unsigned short* eg1 = Eb + (size_t)(m0 + (fb >> 2)) * LQA + (fb & 3) * 8;
  const unsigned short* bg0 = Bb + (size_t)(n0 + (fa >> 2)) * LQA + (fa & 3) * 8;
  const unsigned short* bg1 = Bb + (size_t)(n0 + (fb >> 2)) * LQA + (fb & 3) * 8;
  unsigned short* As0 = As + w * 512;
  unsigned short* As1 = As + (4 + w) * 512;
  unsigned short* Bs0 = Bs + w * 512;
  unsigned short* Bs1 = Bs + (4 + w) * 512;

  f32x4 acc[4][4];
#pragma unroll
  for (int i = 0; i < 4; ++i)
#pragma unroll
    for (int j = 0; j < 4; ++j) acc[i][j] = (f32x4)0.f;

  for (int kt = 0; kt < LQA / 32; ++kt) {
    const int ko = kt * 32;
    gload_lds16(eg0 + ko, As0);
    gload_lds16(eg1 + ko, As1);
    gload_lds16(bg0 + ko, Bs0);
    gload_lds16(bg1 + ko, Bs1);
    __syncthreads();
    s16x8 af[4], bfr[4];
#pragma unroll
    for (int i = 0; i < 4; ++i) {
      af[i]  = *(const s16x8*)&As[(moff + i * 16 + lrow) * 32 + quad * 8];
      bfr[i] = *(const s16x8*)&Bs[(noff + i * 16 + lrow) * 32 + quad * 8];
    }
#pragma unroll
    for (int i = 0; i < 4; ++i)
#pragma unroll
      for (int j = 0; j < 4; ++j)
        acc[i][j] = __builtin_amdgcn_mfma_f32_16x16x32_bf16(af[i], bfr[j], acc[i][j], 0, 0, 0);
    __syncthreads();
  }

  // Epilogue: normalize + uniform-row term, fp32 stores into concat right half
  const float2* ia = invadd + b * LQA;
  const float* bs = bsum + b * HD;
  float* ob = outp + (size_t)b * LQA * 1024;
#pragma unroll
  for (int i = 0; i < 4; ++i) {
#pragma unroll
    for (int j = 0; j < 4; ++j) {
      int ncol = noff + j * 16 + lrow;
      float bsv = bs[n0 + ncol];
#pragma unroll
      for (int r = 0; r < 4; ++r) {
        int mrow = moff + i * 16 + quad * 4 + r;
        float2 v = ia[m0 + mrow];
        ob[(size_t)(m0 + mrow) * 1024 + 512 + n0 + ncol] =
            v.x * acc[i][j][r] + v.y * bsv;
      }
    }
  }
}

// ---------------------------------------------------------------------------
extern "C" void kernel_launch(void* const* d_in, const int* in_sizes, int n_in,
                              void* d_out, int out_size, void* d_ws, size_t ws_size,
                              hipStream_t stream) {
  (void)in_sizes; (void)n_in; (void)out_size; (void)ws_size;
  const float* q    = (const float*)d_in[0];
  const float* a    = (const float*)d_in[1];
  const int*   qm   = (const int*)d_in[2];
  const int*   am   = (const int*)d_in[3];
  const float* temp = (const float*)d_in[4];

  float* out0 = (float*)d_out;                         // [NB][LQA][1024] concat(q, q_s)
  float* out1 = out0 + (size_t)NB * LQA * 1024;        // [NB][LQA][1024] concat(a, a_s)

  char* ws = (char*)d_ws;
  const size_t MB = 1024ull * 1024ull;
  unsigned short* E    = (unsigned short*)(ws);                 //  64 MB
  unsigned short* ET   = (unsigned short*)(ws + 64 * MB);       //  64 MB
  unsigned short* qT   = (unsigned short*)(ws + 128 * MB);      //  32 MB
  unsigned short* aT   = (unsigned short*)(ws + 160 * MB);      //  32 MB
  unsigned short* qb16 = (unsigned short*)(ws + 192 * MB);      //  32 MB
  unsigned short* ab16 = (unsigned short*)(ws + 224 * MB);      //  32 MB
  float*  sums  = (float*)(ws + 256 * MB);                      // rowsumE|colsumE 256 KB
  float2* invadd= (float2*)(ws + 256 * MB + (256 << 10));       // invq|inva 512 KB
  float*  qsum  = (float*)(ws + 256 * MB + (768 << 10));        //  64 KB
  float*  asum  = (float*)(ws + 256 * MB + (832 << 10));        //  64 KB

  k_transpose_copy<<<dim3(8, 16, NB), 256, 0, stream>>>(q, out0, qT, qb16);
  k_transpose_copy<<<dim3(8, 16, NB), 256, 0, stream>>>(a, out1, aT, ab16);
  hipMemsetAsync(sums, 0, (size_t)2 * NB * LQA * sizeof(float), stream);
  k_rowsum_plain<<<dim3(NB * HD / 16), 256, 0, stream>>>(qT, qsum);  // sum_q q[:,h]
  k_rowsum_plain<<<dim3(NB * HD / 16), 256, 0, stream>>>(aT, asum);  // sum_a a[:,h]
  k_scores<<<dim3(2048), 256, 0, stream>>>(qb16, ab16, qm, am, temp,
                                           E, ET, sums, sums + NB * LQA);
  k_stats<<<dim3(2 * NB * LQA / 256), 256, 0, stream>>>(sums, invadd);
  k_agg<<<dim3(1024), 256, 0, stream>>>(E,  aT, invadd,            asum, out0);  // q_s
  k_agg<<<dim3(1024), 256, 0, stream>>>(ET, qT, invadd + NB * LQA, qsum, out1);  // a_s
}